// Round 5
// baseline (107.822 us; speedup 1.0000x reference)
//
#include <hip/hip_runtime.h>

// Quantum conv circuit, 16 qubits, batch 16.
// Round 13: dependency-level cutting (from r12's 105.0us 2-pass).
// r12 lesson: removing a dispatch+roundtrip gained only 2.6us -> kernels are
// DS-latency-CHAIN bound (~40 serial shuffle levels x ~120cy). This round fuses:
//  - lgate2<M0,M1>: two commuting lane gates in ONE shuffle level (3 shfl_xor
//    partners, 8-term combine; same per-slot FMA count as two lgates).
//  - cswapN: 2-3 sequential CNOT lane-swaps (disjoint bit sets) composed into ONE
//    ds_bpermute level with computed source lane.
// DS levels: pass A 17->11, pass B 26->17. Everything else verbatim r12.
// Pass A: tile b0..b11 (outer b12..15); Pass B: tile rest (outer b2,b4,b6,b8).
// 256 blocks x 1024 threads, 4 amps/thread. st = float2[16][65536] at d_ws;
// tbl (540 floats) at d_ws + 8MB. bit p = 15-wire.
// Gate idx: L1d0(p)=15-p, L1d1(p)=16+(15-p), L2d0(p)=32+(15-p)/2, L2d1(p)=40+(15-p)/2,
//           L3d0(p)=48+(15-p)/4, L3d1(p)=52+(15-p)/4, L4d0(p)=56+(15-p)/8, L4d1=58,59.

#define DEV __device__ __forceinline__

__device__ static const unsigned char G_CP[60] = {
  15,14,13,12,11,10,9,8,7,6,5,4,3,2,1,0,
  15,14,13,12,11,10,9,8,7,6,5,4,3,2,1,0,
  15,13,11,9,7,5,3,1,
  15,13,11,9,7,5,3,1,
  15,11,7,3,
  15,11,7,3,
  15,7,
  15,7
};
__device__ static const unsigned char G_CQ[60] = {
  14,13,12,11,10,9,8,7,6,5,4,3,2,1,0,15,
  14,13,12,11,10,9,8,7,6,5,4,3,2,1,0,15,
  13,11,9,7,5,3,1,15,
  13,11,9,7,5,3,1,15,
  11,7,3,15,
  11,7,3,15,
  7,15,
  7,15
};

DEV float2 F2(float x, float y){ float2 r; r.x = x; r.y = y; return r; }
DEV float2 cmulf(float2 a, float2 b){ return F2(a.x*b.x - a.y*b.y, a.x*b.y + a.y*b.x); }
DEV int swz(int j){ return j ^ ((j>>4)&15) ^ ((j>>8)&15); }
DEV int sw2(int m){
  return m ^ ((m>>9)&1) ^ (((m>>11)&1)<<1)
           ^ ((((m>>3)&1)^((m>>8)&1))<<2)
           ^ ((((m>>4)&1)^((m>>5)&1)^((m>>10)&1))<<3);
}

// ---- permlane32_swap(a,b): r[0] = (lane<32)? self:partner = x0;
//      r[1] = (lane<32)? partner:self = x1.  (HW-verified r11c) ----
#if __has_builtin(__builtin_amdgcn_permlane32_swap)
#define HAVE_PLS 1
DEV void plswap01(float &x0, float &x1){
  auto r = __builtin_amdgcn_permlane32_swap(__float_as_uint(x0), __float_as_uint(x1), false, false);
  x0 = __uint_as_float((unsigned)r[0]);
  x1 = __uint_as_float((unsigned)r[1]);
}
#else
#define HAVE_PLS 0
#endif

// gate on register slot bit SB
template<int SB>
DEV void gate4(float2* a, const float* __restrict__ g){
  float u00r=g[0],u00i=g[1],u01r=g[2],u01i=g[3],u10r=g[4],u10i=g[5],u11r=g[6],u11i=g[7];
  #pragma unroll
  for (int m=0;m<2;m++){
    int i0 = (SB==0) ? (m<<1) : m;
    int i1 = i0 | (1<<SB);
    float2 x0=a[i0], x1=a[i1];
    a[i0] = F2(u00r*x0.x - u00i*x0.y + u01r*x1.x - u01i*x1.y,
               u00r*x0.y + u00i*x0.x + u01r*x1.y + u01i*x1.x);
    a[i1] = F2(u10r*x0.x - u10i*x0.y + u11r*x1.x - u11i*x1.y,
               u10r*x0.y + u10i*x0.x + u11r*x1.y + u11i*x1.x);
  }
}

// single lane-bit gate: new = A*self + B*partner, A = h? u11:u00, B = h? u10:u01.
DEV void lgate(float2* a, const float* __restrict__ g, int mask, int lane){
  bool h = (lane & mask) != 0;
  float Ar = h ? g[6] : g[0], Ai = h ? g[7] : g[1];
  float Br = h ? g[4] : g[2], Bi = h ? g[5] : g[3];
  #pragma unroll
  for (int s=0;s<4;s++){
    float px = __shfl_xor(a[s].x, mask);
    float py = __shfl_xor(a[s].y, mask);
    a[s] = F2(Ar*a[s].x - Ai*a[s].y + Br*px - Bi*py,
              Ar*a[s].y + Ai*a[s].x + Br*py + Bi*px);
  }
}

// FUSED pair of commuting lane gates (g0 on bit M0, g1 on bit M1) in one shuffle
// level. Row coefficients: A=U[h][h] (self), B=U[h][1-h] (partner). Combined:
// new = (A0*A1)*self + (B0*A1)*p(M0) + (A0*B1)*p(M1) + (B0*B1)*p(M0|M1).
template<int M0,int M1>
DEV void lgate2(float2* a, const float* __restrict__ g0, const float* __restrict__ g1, int lane){
  bool h0 = (lane & M0) != 0, h1 = (lane & M1) != 0;
  float A0r = h0?g0[6]:g0[0], A0i = h0?g0[7]:g0[1];
  float B0r = h0?g0[4]:g0[2], B0i = h0?g0[5]:g0[3];
  float A1r = h1?g1[6]:g1[0], A1i = h1?g1[7]:g1[1];
  float B1r = h1?g1[4]:g1[2], B1i = h1?g1[5]:g1[3];
  float Sr = A0r*A1r - A0i*A1i, Si = A0r*A1i + A0i*A1r;
  float Pr = B0r*A1r - B0i*A1i, Pi = B0r*A1i + B0i*A1r;
  float Tr = A0r*B1r - A0i*B1i, Ti = A0r*B1i + A0i*B1r;
  float Qr = B0r*B1r - B0i*B1i, Qi = B0r*B1i + B0i*B1r;
  #pragma unroll
  for (int s=0;s<4;s++){
    float x = a[s].x, y = a[s].y;
    float p0x = __shfl_xor(x, M0),    p0y = __shfl_xor(y, M0);
    float p1x = __shfl_xor(x, M1),    p1y = __shfl_xor(y, M1);
    float qx  = __shfl_xor(x, M0|M1), qy  = __shfl_xor(y, M0|M1);
    a[s] = F2(Sr*x - Si*y + Pr*p0x - Pi*p0y + Tr*p1x - Ti*p1y + Qr*qx - Qi*qy,
              Sr*y + Si*x + Pr*p0y + Pi*p0x + Tr*p1y + Ti*p1x + Qr*qy + Qi*qx);
  }
}

// mask-32 lane gate via permlane32_swap (VALU, no DS level)
DEV void lgate32(float2* a, const float* __restrict__ g, int lane){
#if HAVE_PLS
  bool h = (lane & 32) != 0;
  float c0r = h ? g[4] : g[0], c0i = h ? g[5] : g[1];
  float c1r = h ? g[6] : g[2], c1i = h ? g[7] : g[3];
  #pragma unroll
  for (int s=0;s<4;s++){
    float x0x = a[s].x, x1x = a[s].x, x0y = a[s].y, x1y = a[s].y;
    plswap01(x0x, x1x); plswap01(x0y, x1y);
    a[s] = F2(c0r*x0x - c0i*x0y + c1r*x1x - c1i*x1y,
              c0r*x0y + c0i*x0x + c1r*x1y + c1i*x1x);
  }
#else
  lgate(a, g, 32, lane);
#endif
}

// single CNOT ctrl lane-bit cmask, tgt lane-bit tmask
DEV void cswap(float2* a, int cmask, int tmask, int lane){
  bool c = (lane & cmask) != 0;
  #pragma unroll
  for (int s=0;s<4;s++){
    float px = __shfl_xor(a[s].x, tmask);
    float py = __shfl_xor(a[s].y, tmask);
    if (c){ a[s].x = px; a[s].y = py; }
  }
}

// FUSED sequential CNOT lane-swaps with pairwise-disjoint (ctrl,tgt) bit sets:
// one ds_bpermute level, source lane precomputed by caller.
DEV void cswapN(float2* a, int src){
  #pragma unroll
  for (int s=0;s<4;s++){
    a[s].x = __shfl(a[s].x, src);
    a[s].y = __shfl(a[s].y, src);
  }
}

// RZZ: couplings [C0,C0+N0) u [C1,C1+N1). hh[k] = theta3(k)/2; Ib = index, reg bits 0.
template<int C0,int N0,int C1,int N1,unsigned M0,unsigned M1>
DEV void diagx(float2* a, const float* __restrict__ hh, unsigned Ib){
  const unsigned rm = M0|M1;
  float base = 0.f;
  #pragma unroll
  for (int k=C0;k<C0+N0;k++){
    const int p=G_CP[k], q=G_CQ[k];
    if (!(((1u<<p)|(1u<<q)) & rm)){
      float h = hh[k];
      base += (((Ib>>p)^(Ib>>q))&1u) ? h : -h;
    }
  }
  #pragma unroll
  for (int k=C1;k<C1+N1;k++){
    const int p=G_CP[k], q=G_CQ[k];
    if (!(((1u<<p)|(1u<<q)) & rm)){
      float h = hh[k];
      base += (((Ib>>p)^(Ib>>q))&1u) ? h : -h;
    }
  }
  #pragma unroll
  for (int r=0;r<4;r++){
    unsigned Ir = Ib ^ ((r&1)?M0:0u) ^ ((r&2)?M1:0u);
    float ph = base;
    #pragma unroll
    for (int k=C0;k<C0+N0;k++){
      const int p=G_CP[k], q=G_CQ[k];
      if (((1u<<p)|(1u<<q)) & rm){
        float h = hh[k];
        ph += (((Ir>>p)^(Ir>>q))&1u) ? h : -h;
      }
    }
    #pragma unroll
    for (int k=C1;k<C1+N1;k++){
      const int p=G_CP[k], q=G_CQ[k];
      if (((1u<<p)|(1u<<q)) & rm){
        float h = hh[k];
        ph += (((Ir>>p)^(Ir>>q))&1u) ? h : -h;
      }
    }
    float c, s;
    __sincosf(ph, &s, &c);
    a[r] = cmulf(a[r], F2(c, s));
  }
}

// ---- per-block gate-table build (f32) ----
DEV void build_entry(float* sh, const float* __restrict__ p0, const float* __restrict__ p1,
                     const float* __restrict__ p2, const float* __restrict__ p3, int g){
  int d, j, n; const float* P;
  if (g < 32)      { n=16; d=(g>>4)&1; j=g&15; P=p0; }
  else if (g < 48) { n=8;  d=(g>>3)&1; j=g&7;  P=p1; }
  else if (g < 56) { n=4;  d=(g>>2)&1; j=g&3;  P=p2; }
  else             { n=2;  d=(g>>1)&1; j=g&1;  P=p3; }
  int base = 4*j + 4*n*d;
  float th0 = P[base+0], th1 = P[base+1], th2 = P[base+2], th3 = P[base+3];
  float c0,s0,ca,sa,c2,s2;
  sincosf(0.5f*th0, &s0, &c0);
  sincosf(0.5f*th1, &sa, &ca);
  sincosf(0.5f*th2, &s2, &c2);
  float B00r =  ca*c0, B00i = -sa*c0;
  float B01r = -sa*s0, B01i = -ca*s0;
  float B10r =  sa*s0, B10i = -ca*s0;
  float B11r =  ca*c0, B11i =  sa*c0;
  float* o8 = sh + g*8;
  o8[0]=c2*B00r + s2*B10i; o8[1]=c2*B00i - s2*B10r;
  o8[2]=c2*B01r + s2*B11i; o8[3]=c2*B01i - s2*B11r;
  o8[4]=s2*B00i + c2*B10r; o8[5]=-s2*B00r + c2*B10i;
  o8[6]=s2*B01i + c2*B11r; o8[7]=-s2*B01r + c2*B11i;
  sh[480 + g] = 0.5f*th3;
}

// ======== pass A: tile j = b0..b11 (identity), outer o = b12..b15 ========
// Layout A: reg=(b0,b1), lane=(b2..b7), wave=(b8..b11)  [j = (t<<2)|s]
// Layout B: reg=(b10,b11), lane=(b8,b9,b6,b7,b4,b5), wave=(b0..b3)
// Store: addr = (batch<<16)|(o<<12)|(wv<<8)|(lane<<2)|s  (linear, wave-contiguous 2KB)
__global__ __launch_bounds__(1024, 4)
void k_pa(const float* __restrict__ xre, const float* __restrict__ xim,
          const float* __restrict__ pp0, const float* __restrict__ pp1,
          const float* __restrict__ pp2, const float* __restrict__ pp3,
          float* __restrict__ tbl, float2* __restrict__ st, float* __restrict__ out){
  const int t = threadIdx.x, lane = t & 63, wv = t >> 6;   // wv 0..15
  const int batch = blockIdx.x >> 4, o = blockIdx.x & 15;
  const unsigned hi = ((unsigned)batch<<16) | ((unsigned)o<<12);
  __shared__ float2 lds[4096];
  __shared__ float sh[544];
  float2 a[4];
  { // load layout A (contiguous; issues before table build)
    unsigned base = hi | ((unsigned)t<<2);
    float4 re = *(const float4*)(xre + base);
    float4 im = *(const float4*)(xim + base);
    a[0]=F2(re.x,im.x); a[1]=F2(re.y,im.y); a[2]=F2(re.z,im.z); a[3]=F2(re.w,im.w);
  }
  if (t < 60) build_entry(sh, pp0, pp1, pp2, pp3, t);
  if (blockIdx.x == 0 && t >= 64 && t < 80) out[t - 64] = 0.f;
  __syncthreads();
  if (blockIdx.x == 0){
    for (int i = t; i < 540; i += 1024) tbl[i] = sh[i];
  }
  #define LTB(i) (sh + (i)*8)
  const float* HH = sh + 480;
  // ---- layout A ----
  gate4<0>(a, LTB(15)); gate4<1>(a, LTB(14));                    // L1d0 b0,b1
  lgate2<1,2>(a, LTB(13), LTB(12), lane);                        // b2,b3 (1 level)
  lgate2<4,8>(a, LTB(11), LTB(10), lane);                        // b4,b5 (1 level)
  lgate(a, LTB(9),16,lane); lgate32(a, LTB(8),lane);             // b6,b7
  const unsigned IbA = ((unsigned)o<<12) | ((unsigned)wv<<8) | ((unsigned)lane<<2);
  diagx<8,7,0,0,1u,2u>(a, HH, IbA);                              // D0 (7,6)..(1,0)
  gate4<1>(a, LTB(30));                                          // L1d1 b1
  lgate2<1,2>(a, LTB(29), LTB(28), lane);                        // b2,b3
  lgate2<4,8>(a, LTB(27), LTB(26), lane);                        // b4,b5
  lgate(a, LTB(25),16,lane);                                     // b6
  diagx<25,5,0,0,1u,2u>(a, HH, IbA);                             // D1 (6,5)..(2,1)
  { // CNOT 3->2 then 5->4 (disjoint {2,1},{8,4}) fused
    int src = lane ^ ((lane&2)?1:0) ^ ((lane&8)?4:0);
    cswapN(a, src);
  }
  // ---- exchange ----
  #pragma unroll
  for (int s=0;s<4;s++) lds[swz((t<<2)|s)] = a[s];
  __syncthreads();
  const int idxR = (wv&15) | (((lane>>4)&1)<<4) | (((lane>>5)&1)<<5)
                 | (((lane>>2)&1)<<6) | (((lane>>3)&1)<<7)
                 | ((lane&1)<<8) | (((lane>>1)&1)<<9);
  #pragma unroll
  for (int s=0;s<4;s++) a[s] = lds[swz(idxR | ((s&1)<<10) | (((s>>1)&1)<<11))];
  // ---- layout B ----
  lgate2<1,2>(a, LTB(7), LTB(6), lane);                          // L1d0 b8,b9
  gate4<0>(a, LTB(5)); gate4<1>(a, LTB(4));                      // L1d0 b10,b11
  const unsigned IbB = ((unsigned)o<<12) | (unsigned)idxR;
  diagx<4,4,0,0,1024u,2048u>(a, HH, IbB);                        // D0 (11,10)..(8,7)
  lgate2<1,2>(a, LTB(23), LTB(22), lane);                        // L1d1 b8,b9
  lgate(a, LTB(24),8,lane);                                      // L1d1 b7
  gate4<0>(a, LTB(21));                                          // L1d1 b10
  diagx<21,4,0,0,1024u,2048u>(a, HH, IbB);                       // D1 (10,9)..(7,6)
  { // CNOT 7->6 then 9->8 (disjoint {8,4},{2,1}) fused
    int src = lane ^ ((lane&8)?4:0) ^ ((lane&2)?1:0);
    cswapN(a, src);
  }
  {
    unsigned sb = hi | ((unsigned)wv<<8) | ((unsigned)lane<<2);
    float4 v0, v1;
    v0.x=a[0].x; v0.y=a[0].y; v0.z=a[1].x; v0.w=a[1].y;
    v1.x=a[2].x; v1.y=a[2].y; v1.z=a[3].x; v1.w=a[3].y;
    *(float4*)(st + sb) = v0;
    *(float4*)(st + sb + 2) = v1;
  }
  #undef LTB
}

#define TBL(i) (tbl + (i)*8)

// ======== pass B: tile m: m0..m11 -> b{0,1,3,5,7,9,10,11,12,13,14,15}; outer b{2,4,6,8}
// Layout A: reg=(b10,b11); lane=(b12,b13,b14,b15,b0,b1); wave=(b3,b5,b7,b9)
// Layout B: reg=(b1,b3); lane=(b5,b7,b9,b11,b13,b15); wave=(b0,b10,b12,b14)
__global__ __launch_bounds__(1024, 4)
void k_pb(const float* __restrict__ tbl, float2* __restrict__ st, float* __restrict__ out){
  const int t = threadIdx.x, lane = t & 63, wv = t >> 6;
  const int batch = blockIdx.x >> 4, o = blockIdx.x & 15;
  __shared__ float2 lds[4096];
  __shared__ float red[16];
  const float* HH = tbl + 480;
  const unsigned opart = ((unsigned)(o&1)<<2) | ((unsigned)((o>>1)&1)<<4)
                       | ((unsigned)((o>>2)&1)<<6) | ((unsigned)((o>>3)&1)<<8);
  float2 a[4];
  { // gather: inverse of pass-A store permutation; 32B contiguous per thread
    unsigned gb = ((unsigned)batch<<16)
      | (((unsigned)(o>>3)&1)<<2) | (((unsigned)(o>>2)&1)<<4)
      | (((unsigned)(o>>1)&1)<<6) | (((unsigned)o&1)<<10)
      | (((unsigned)(wv>>3)&1)<<3) | (((unsigned)(wv>>2)&1)<<5)
      | (((unsigned)(wv>>1)&1)<<7) | (((unsigned)wv&1)<<11)
      | (((unsigned)(lane>>4)&1)<<8) | (((unsigned)(lane>>5)&1)<<9)
      | (((unsigned)lane&1)<<12) | (((unsigned)(lane>>1)&1)<<13)
      | (((unsigned)(lane>>2)&1)<<14) | (((unsigned)(lane>>3)&1)<<15);
    const float4* sp = (const float4*)(st + gb);
    float4 lo = sp[0], hi4 = sp[1];
    a[0]=F2(lo.x,lo.y); a[1]=F2(lo.z,lo.w); a[2]=F2(hi4.x,hi4.y); a[3]=F2(hi4.z,hi4.w);
  }
  const unsigned IbA = opart
    | (((unsigned)lane&1)<<12) | (((unsigned)(lane>>1)&1)<<13)
    | (((unsigned)(lane>>2)&1)<<14) | (((unsigned)(lane>>3)&1)<<15)
    | (((unsigned)(lane>>4)&1)<<0) | (((unsigned)(lane>>5)&1)<<1)
    | (((unsigned)wv&1)<<3) | (((unsigned)(wv>>1)&1)<<5)
    | (((unsigned)(wv>>2)&1)<<7) | (((unsigned)(wv>>3)&1)<<9);
  // ---- layout A ----
  lgate2<1,2>(a, TBL(3), TBL(2), lane);                          // L1d0 b12,b13
  lgate2<4,8>(a, TBL(1), TBL(0), lane);                          // b14,b15
  diagx<0,4,15,1,1024u,2048u>(a, HH, IbA);                       // D0 k0..3,k15
  lgate(a, TBL(31),16,lane);                                     // L1d1 b0
  gate4<1>(a, TBL(20));                                          // L1d1 b11
  lgate2<1,2>(a, TBL(19), TBL(18), lane);                        // b12,b13
  lgate2<4,8>(a, TBL(17), TBL(16), lane);                        // b14,b15
  diagx<16,5,30,2,1024u,2048u>(a, HH, IbA);                      // D1 k16..20,k30,k31
  { // CNOT 15->14, 13->12, 1->0 fused (disjoint {8,4},{2,1},{32,16})
    int src = lane ^ ((lane&8)?4:0) ^ ((lane&2)?1:0) ^ ((lane&32)?16:0);
    cswapN(a, src);
  }
  { float2 tmp=a[2]; a[2]=a[3]; a[3]=tmp; }                      // CNOT 11->10 (reg)
  // ---- exchange ----
  const int idxW = ((lane>>4)&1) | (((lane>>5)&1)<<1)
                 | ((wv&1)<<2) | (((wv>>1)&1)<<3) | (((wv>>2)&1)<<4) | (((wv>>3)&1)<<5)
                 | ((lane&1)<<8) | (((lane>>1)&1)<<9)
                 | (((lane>>2)&1)<<10) | (((lane>>3)&1)<<11);
  #pragma unroll
  for (int s=0;s<4;s++) lds[sw2(idxW | ((s&1)<<6) | (((s>>1)&1)<<7))] = a[s];
  __syncthreads();
  const int idxR = (wv&1) | (((wv>>1)&1)<<6) | (((wv>>2)&1)<<8) | (((wv>>3)&1)<<10)
                 | ((lane&1)<<3) | (((lane>>1)&1)<<4) | (((lane>>2)&1)<<5)
                 | (((lane>>3)&1)<<7) | (((lane>>4)&1)<<9) | (((lane>>5)&1)<<11);
  #pragma unroll
  for (int s=0;s<4;s++) a[s] = lds[sw2(idxR | ((s&1)<<1) | (((s>>1)&1)<<2))];
  // ---- layout B ----
  const unsigned IbB = opart
    | (((unsigned)wv&1)<<0) | (((unsigned)(wv>>1)&1)<<10)
    | (((unsigned)(wv>>2)&1)<<12) | (((unsigned)(wv>>3)&1)<<14)
    | (((unsigned)lane&1)<<5) | (((unsigned)(lane>>1)&1)<<7)
    | (((unsigned)(lane>>2)&1)<<9) | (((unsigned)(lane>>3)&1)<<11)
    | (((unsigned)(lane>>4)&1)<<13) | (((unsigned)(lane>>5)&1)<<15);
  // L2d0
  gate4<0>(a, TBL(39)); gate4<1>(a, TBL(38));
  lgate2<1,2>(a, TBL(37), TBL(36), lane);
  lgate2<4,8>(a, TBL(35), TBL(34), lane);
  lgate(a, TBL(33),16,lane); lgate32(a, TBL(32),lane);
  diagx<32,8,0,0,2u,8u>(a, HH, IbB);
  // L2d1
  gate4<0>(a, TBL(47)); gate4<1>(a, TBL(46));
  lgate2<1,2>(a, TBL(45), TBL(44), lane);
  lgate2<4,8>(a, TBL(43), TBL(42), lane);
  lgate(a, TBL(41),16,lane); lgate32(a, TBL(40),lane);
  diagx<40,8,0,0,2u,8u>(a, HH, IbB);
  { // sigma2: (g15->g13),(g11->g9),(g7->g5) fused (disjoint {32,16},{8,4},{2,1})
    int src = lane ^ ((lane&32)?16:0) ^ ((lane&8)?4:0) ^ ((lane&2)?1:0);
    cswapN(a, src);
  }
  { float2 tmp=a[2]; a[2]=a[3]; a[3]=tmp; }                      // (g3->g1) reg
  // L3d0 {g15,g11,g7,g3}
  lgate2<8,2>(a, TBL(49), TBL(50), lane);
  lgate32(a, TBL(48),lane);
  gate4<1>(a, TBL(51));
  diagx<48,4,0,0,2u,8u>(a, HH, IbB);
  // L3d1
  lgate2<8,2>(a, TBL(53), TBL(54), lane);
  lgate32(a, TBL(52),lane);
  gate4<1>(a, TBL(55));
  diagx<52,4,0,0,2u,8u>(a, HH, IbB);
  // sigma3: (g15->g11) in-wave; (g7->g3): ctrl lane bit1, tgt reg s1
  cswap(a, 32, 8, lane);
  if (lane & 2){
    float2 t0=a[0]; a[0]=a[2]; a[2]=t0;
    float2 t1=a[1]; a[1]=a[3]; a[3]=t1;
  }
  // L4d0 {g15,g7}, D4_0, L4d1 g15
  lgate32(a, TBL(56),lane); lgate(a, TBL(57),2,lane);
  diagx<56,2,0,0,2u,8u>(a, HH, IbB);
  lgate32(a, TBL(58),lane);
  // measure Z on g15 = lane bit5
  float sl = 0.f;
  #pragma unroll
  for (int s=0;s<4;s++) sl += a[s].x*a[s].x + a[s].y*a[s].y;
  float sg = (lane & 32) ? -sl : sl;
  #pragma unroll
  for (int off=32; off>0; off>>=1) sg += __shfl_down(sg, off);
  if ((t & 63) == 0) red[wv] = sg;
  __syncthreads();
  if (t == 0){
    float tot = 0.f;
    #pragma unroll
    for (int w=0; w<16; w++) tot += red[w];
    atomicAdd(out + batch, tot);
  }
}

extern "C" void kernel_launch(void* const* d_in, const int* in_sizes, int n_in,
                              void* d_out, int out_size, void* d_ws, size_t ws_size,
                              hipStream_t stream) {
  const float* xre = (const float*)d_in[0];
  const float* xim = (const float*)d_in[1];
  const float* p0  = (const float*)d_in[2];
  const float* p1  = (const float*)d_in[3];
  const float* p2  = (const float*)d_in[4];
  const float* p3  = (const float*)d_in[5];
  float* out = (float*)d_out;
  float2* st = (float2*)d_ws;                           // 8 MB state
  float* tbl = (float*)((char*)d_ws + (8u<<20));        // 540-float gate table

  k_pa<<<256, 1024, 0, stream>>>(xre, xim, p0, p1, p2, p3, tbl, st, out);
  k_pb<<<256, 1024, 0, stream>>>(tbl, st, out);
}